// Round 9
// baseline (322.312 us; speedup 1.0000x reference)
//
#include <hip/hip_runtime.h>

typedef short v8s __attribute__((ext_vector_type(8)));
typedef _Float16 v8h __attribute__((ext_vector_type(8)));
typedef float v4f __attribute__((ext_vector_type(4)));
typedef unsigned short u16;

// All on-chip/intermediate tensors are fp16: values bounded (L2-normed Q/K,
// |S|<=1/temp, A<=1, conv outputs O(1)), so fp16 beats bf16 accuracy AND
// f32->f16 is 1 VALU op. MFMA f16 rate == bf16 rate on gfx950.
#define MFMA_F16(a, b, c) __builtin_amdgcn_mfma_f32_16x16x32_f16((a), (b), (c), 0, 0, 0)
#define XS 72   // row stride in 16-bit elems (144 B, 16B-aligned rows)

__device__ __forceinline__ u16 f16r(float x) {
    _Float16 h = (_Float16)x; u16 u; __builtin_memcpy(&u, &h, 2); return u;
}
__device__ __forceinline__ float f16f(u16 u) {
    _Float16 h; __builtin_memcpy(&h, &u, 2); return (float)h;
}

// ---------------------------------------------------------------------------
// 2-WINDOW INTERLEAVE: every phase runs tile-A then tile-B between the same
// barriers. The two chains are independent -> phase time ~= latency(1 chain)
// + throughput(2x work). Rationale: R2/R5/R6/R8 eliminated occupancy, VALU
// count, conflicts, and scheduling hints as levers; all pipes <45% busy ->
// latency-convoy-bound. Per-tile schedules are verbatim the harness-verified
// round-5 k1 (8-barrier/3-buffer) and round-7 k2 (7-barrier/3-buffer).
// LDS: 6 x 9216 = 55296 B (static limit 64 KB) -> 2 blocks/CU.
// ---------------------------------------------------------------------------
__device__ __forceinline__ void mm_frags(const u16* __restrict__ Ag,
                                         const u16* __restrict__ XB,
                                         int wv, int L, int q, v4f C[4])
{
#pragma unroll
    for (int nt = 0; nt < 4; ++nt) C[nt] = (v4f){0.f, 0.f, 0.f, 0.f};
#pragma unroll
    for (int kt = 0; kt < 2; ++kt) {
        v8h a = *(const v8h*)(Ag + (16 * wv + L) * 64 + kt * 32 + q * 8);
#pragma unroll
        for (int nt = 0; nt < 4; ++nt) {
            v8h b = *(const v8h*)(XB + (nt * 16 + L) * XS + kt * 32 + q * 8);
            C[nt] = MFMA_F16(a, b, C[nt]);
        }
    }
}
__device__ __forceinline__ void mm_store(const v4f C[4], u16* __restrict__ M,
                                         int wv, int L, int q)
{
    const int rowb = 16 * wv + 4 * q;
#pragma unroll
    for (int r = 0; r < 4; ++r)
#pragma unroll
        for (int nt = 0; nt < 4; ++nt)
            M[(rowb + r) * XS + nt * 16 + L] = f16r(C[nt][r]);
}
__device__ __forceinline__ void mm_stage(const u16* __restrict__ Ag,
                                         const u16* __restrict__ XB,
                                         u16* __restrict__ M,
                                         int wv, int L, int q)
{
    v4f C[4];
    mm_frags(Ag, XB, wv, L, q, C);
    mm_store(C, M, wv, L, q);
}

// dw 3x3 input read: channel c, spatial rows r0-1..r0+2 from fp16 [c][p].
__device__ __forceinline__ void dw_read(const u16* __restrict__ M, int c, int r0,
                                        v8s raw[4])
{
#pragma unroll
    for (int r = 0; r < 4; ++r) {
        const int rr = r0 - 1 + r;
        raw[r] = ((unsigned)rr < 8u) ? *(const v8s*)(M + c * XS + rr * 8)
                                     : (v8s){0, 0, 0, 0, 0, 0, 0, 0};
    }
}

// dw 3x3 compute + optional L2-norm + f16 write.
// TR=false: [c][p] row-major (v8s packed). TR=true: transposed [p][c] scalar.
template <bool TR, bool NORM>
__device__ __forceinline__ void dw_write(const float* __restrict__ dwg,
                                         const v8s raw[4], int c, int r0,
                                         u16* __restrict__ Out)
{
    float w[9];
#pragma unroll
    for (int k = 0; k < 9; ++k) w[k] = dwg[c * 9 + k];
    float in[4][10];
#pragma unroll
    for (int r = 0; r < 4; ++r) {
        in[r][0] = 0.f; in[r][9] = 0.f;
#pragma unroll
        for (int j = 0; j < 8; ++j) in[r][j + 1] = f16f((u16)raw[r][j]);
    }
    float o[2][8];
#pragma unroll
    for (int rr = 0; rr < 2; ++rr)
#pragma unroll
        for (int j = 0; j < 8; ++j) {
            float s;
            s = w[0] * in[rr][j];
            s = fmaf(w[1], in[rr][j + 1], s);
            s = fmaf(w[2], in[rr][j + 2], s);
            s = fmaf(w[3], in[rr + 1][j], s);
            s = fmaf(w[4], in[rr + 1][j + 1], s);
            s = fmaf(w[5], in[rr + 1][j + 2], s);
            s = fmaf(w[6], in[rr + 2][j], s);
            s = fmaf(w[7], in[rr + 2][j + 1], s);
            s = fmaf(w[8], in[rr + 2][j + 2], s);
            o[rr][j] = s;
        }
    if (NORM) {
        float ss = 0.f;
#pragma unroll
        for (int rr = 0; rr < 2; ++rr)
#pragma unroll
            for (int j = 0; j < 8; ++j) ss = fmaf(o[rr][j], o[rr][j], ss);
        ss += __shfl_xor(ss, 1);
        ss += __shfl_xor(ss, 2);
        const float sc = 1.0f / fmaxf(sqrtf(ss), 1e-12f);
#pragma unroll
        for (int rr = 0; rr < 2; ++rr)
#pragma unroll
            for (int j = 0; j < 8; ++j) o[rr][j] *= sc;
    }
    if (TR) {
#pragma unroll
        for (int rr = 0; rr < 2; ++rr)
#pragma unroll
            for (int j = 0; j < 8; ++j)
                Out[((r0 + rr) * 8 + j) * XS + c] = f16r(o[rr][j]);
    } else {
#pragma unroll
        for (int rr = 0; rr < 2; ++rr) {
            v8s v;
#pragma unroll
            for (int j = 0; j < 8; ++j) v[j] = (short)f16r(o[rr][j]);
            *(v8s*)(Out + c * XS + (r0 + rr) * 8) = v;
        }
    }
}

// 64x64x64 D[m][n] = sum_k A[m][k]*B[n][k], both f16 LDS, wave stripe rows.
__device__ __forceinline__ void mm_lds(const u16* __restrict__ Am,
                                       const u16* __restrict__ Bm,
                                       int wv, int L, int q, v4f C[4])
{
#pragma unroll
    for (int nt = 0; nt < 4; ++nt) C[nt] = (v4f){0.f, 0.f, 0.f, 0.f};
#pragma unroll
    for (int kt = 0; kt < 2; ++kt) {
        v8h a = *(const v8h*)(Am + (16 * wv + L) * XS + kt * 32 + q * 8);
#pragma unroll
        for (int nt = 0; nt < 4; ++nt) {
            v8h b = *(const v8h*)(Bm + (nt * 16 + L) * XS + kt * 32 + q * 8);
            C[nt] = MFMA_F16(a, b, C[nt]);
        }
    }
}

// proj 3x3 dense: A = Wg global f16 [o][tap*64+c], B from Ot LDS [p][c].
__device__ __forceinline__ void proj_mm(const u16* __restrict__ Wg,
                                        const u16* __restrict__ Ot,
                                        int wv, int L, int q, v4f C[4])
{
#pragma unroll
    for (int nt = 0; nt < 4; ++nt) C[nt] = (v4f){0.f, 0.f, 0.f, 0.f};
    const u16* arow = Wg + (16 * wv + L) * 576;
    const int pc = L & 7;
    const int prb = L >> 3;
#pragma unroll
    for (int tap = 0; tap < 9; ++tap) {
        const int dy = tap / 3 - 1, dx = tap % 3 - 1;
        const int spc = pc + dx;
        const bool vc = (unsigned)spc < 8u;
#pragma unroll
        for (int half = 0; half < 2; ++half) {
            v8h a = *(const v8h*)(arow + tap * 64 + half * 32 + q * 8);
#pragma unroll
            for (int nt = 0; nt < 4; ++nt) {
                const int spr = nt * 2 + prb + dy;
                v8h b = (v8h)0;
                if (vc && (unsigned)spr < 8u)
                    b = *(const v8h*)(Ot + (spr * 8 + spc) * XS + half * 32 + q * 8);
                C[nt] = MFMA_F16(a, b, C[nt]);
            }
        }
    }
}

// softmax over rows in S[4] C-frags, write A f16 to Am (wave-local rows).
__device__ __forceinline__ void softmax_to_lds(v4f S[4], float invt,
                                               u16* __restrict__ Am,
                                               int rowb, int L)
{
#pragma unroll
    for (int nt = 0; nt < 4; ++nt) S[nt] *= invt;
#pragma unroll
    for (int r = 0; r < 4; ++r) {
        float mx = fmaxf(fmaxf(S[0][r], S[1][r]), fmaxf(S[2][r], S[3][r]));
        mx = fmaxf(mx, __shfl_xor(mx, 1));
        mx = fmaxf(mx, __shfl_xor(mx, 2));
        mx = fmaxf(mx, __shfl_xor(mx, 4));
        mx = fmaxf(mx, __shfl_xor(mx, 8));
        float e0 = __expf(S[0][r] - mx);
        float e1 = __expf(S[1][r] - mx);
        float e2 = __expf(S[2][r] - mx);
        float e3 = __expf(S[3][r] - mx);
        float sm = e0 + e1 + e2 + e3;
        sm += __shfl_xor(sm, 1);
        sm += __shfl_xor(sm, 2);
        sm += __shfl_xor(sm, 4);
        sm += __shfl_xor(sm, 8);
        const float ri = 1.0f / sm;
        Am[(rowb + r) * XS + L +  0] = f16r(e0 * ri);
        Am[(rowb + r) * XS + L + 16] = f16r(e1 * ri);
        Am[(rowb + r) * XS + L + 32] = f16r(e2 * ri);
        Am[(rowb + r) * XS + L + 48] = f16r(e3 * ri);
    }
}

// ---------------------------------------------------------------------------
// Weight prep: fp32 -> f16; proj weights permuted [o][c][tap] -> [o][tap*64+c].
// ---------------------------------------------------------------------------
__global__ void prep(const float* __restrict__ qk_w, const float* __restrict__ v_w,
                     const float* __restrict__ qkv_w, const float* __restrict__ pw0,
                     const float* __restrict__ pw1, u16* __restrict__ Wb)
{
    int i = blockIdx.x * 256 + threadIdx.x;   // 0..98303
    float v;
    if (i < 8192) v = qk_w[i];
    else if (i < 12288) v = v_w[i - 8192];
    else if (i < 24576) v = qkv_w[i - 12288];
    else {
        int j = i - 24576;
        const float* s = pw0;
        if (j >= 36864) { s = pw1; j -= 36864; }
        const int o = j / 576, kk = j % 576;
        const int tap = kk >> 6, c = kk & 63;
        v = s[o * 576 + c * 9 + tap];
    }
    Wb[i] = f16r(v);
}

// ---------------------------------------------------------------------------
// Branch 1, 2 windows/block. Per-tile schedule = round-5 verified 3-buffer:
// B0: Xf -> X -> Vt -> V^T ; B1: Qt -> Qhat -> A ; B2: Kt -> Khat -> O^T.
// 8 barriers.
// ---------------------------------------------------------------------------
__global__ __launch_bounds__(256, 2) void k1(
    const float* __restrict__ x, const float* __restrict__ xf,
    const float* __restrict__ temp_p,
    const float* __restrict__ qk_dw, const float* __restrict__ v_dw,
    const u16* __restrict__ Wqk, const u16* __restrict__ Wv,
    const u16* __restrict__ Wp0,
    u16* __restrict__ midb)
{
    __shared__ u16 B0a[64 * XS], B1a[64 * XS], B2a[64 * XS];
    __shared__ u16 B0b[64 * XS], B1b[64 * XS], B2b[64 * XS];
    const int t = threadIdx.x;
    const int n0 = blockIdx.x << 1, n1 = n0 + 1;
    const int lane = t & 63, wv = t >> 6, L = lane & 15, q = lane >> 4;
    const int rowb = 16 * wv + 4 * q;
    const size_t base0 = (size_t)n0 << 12, base1 = (size_t)n1 << 12;
    const float invt = 1.0f / temp_p[0];
    const int yp = t >> 4, xx0 = (t & 15) << 4;
    const int c2b = (yp >> 3) << 5, ir = (yp & 7) << 3;
    const int dc = t >> 2, dr0 = (t & 3) << 1;

    float4 rx0[4], rx1[4];
    {   // P1: Xf -> B0{a,b}; X loads into rx{0,1}
        const float* sf0 = xf + base0 + yp * 256 + xx0;
        const float* sx0 = x  + base0 + yp * 256 + xx0;
        const float* sf1 = xf + base1 + yp * 256 + xx0;
        const float* sx1 = x  + base1 + yp * 256 + xx0;
#pragma unroll
        for (int k = 0; k < 4; ++k) {
            float4 a0 = *(const float4*)(sf0 + 4 * k);
            float4 a1 = *(const float4*)(sf1 + 4 * k);
            rx0[k] = *(const float4*)(sx0 + 4 * k);
            rx1[k] = *(const float4*)(sx1 + 4 * k);
            const int xx = xx0 + 4 * k;
            const int c = c2b + (xx >> 3), pb = ir + (xx & 7);
            B0a[(pb + 0) * XS + c] = f16r(a0.x);
            B0a[(pb + 1) * XS + c] = f16r(a0.y);
            B0a[(pb + 2) * XS + c] = f16r(a0.z);
            B0a[(pb + 3) * XS + c] = f16r(a0.w);
            B0b[(pb + 0) * XS + c] = f16r(a1.x);
            B0b[(pb + 1) * XS + c] = f16r(a1.y);
            B0b[(pb + 2) * XS + c] = f16r(a1.z);
            B0b[(pb + 3) * XS + c] = f16r(a1.w);
        }
    }
    __syncthreads();                                    // 1
    mm_stage(Wqk,        B0a, B1a, wv, L, q);           // Qt a
    mm_stage(Wqk + 4096, B0a, B2a, wv, L, q);           // Kt a
    mm_stage(Wqk,        B0b, B1b, wv, L, q);           // Qt b
    mm_stage(Wqk + 4096, B0b, B2b, wv, L, q);           // Kt b
    __syncthreads();                                    // 2  (B0 reads done)
    {   // P3: X -> B0{a,b} (overwrite Xf)
#pragma unroll
        for (int k = 0; k < 4; ++k) {
            const int xx = xx0 + 4 * k;
            const int c = c2b + (xx >> 3), pb = ir + (xx & 7);
            B0a[(pb + 0) * XS + c] = f16r(rx0[k].x);
            B0a[(pb + 1) * XS + c] = f16r(rx0[k].y);
            B0a[(pb + 2) * XS + c] = f16r(rx0[k].z);
            B0a[(pb + 3) * XS + c] = f16r(rx0[k].w);
            B0b[(pb + 0) * XS + c] = f16r(rx1[k].x);
            B0b[(pb + 1) * XS + c] = f16r(rx1[k].y);
            B0b[(pb + 2) * XS + c] = f16r(rx1[k].z);
            B0b[(pb + 3) * XS + c] = f16r(rx1[k].w);
        }
    }
    v8s rawQ0[4], rawQ1[4];
    dw_read(B1a, dc, dr0, rawQ0);                       // Qt a
    dw_read(B1b, dc, dr0, rawQ1);                       // Qt b
    __syncthreads();                                    // 3  (X ready; B1 reads done)
    v4f VF0[4], VF1[4];
    mm_frags(Wv, B0a, wv, L, q, VF0);                   // Vt frags a
    mm_frags(Wv, B0b, wv, L, q, VF1);                   // Vt frags b
    dw_write<false, true>(qk_dw, rawQ0, dc, dr0, B1a);  // Qhat a
    dw_write<false, true>(qk_dw, rawQ1, dc, dr0, B1b);  // Qhat b
    v8s rawK0[4], rawK1[4];
    dw_read(B2a, dc, dr0, rawK0);                       // Kt a
    dw_read(B2b, dc, dr0, rawK1);                       // Kt b
    __syncthreads();                                    // 4  (B0/B2 reads done)
    mm_store(VF0, B0a, wv, L, q);                       // Vt a -> B0a in-place
    mm_store(VF1, B0b, wv, L, q);                       // Vt b -> B0b in-place
    dw_write<false, true>(qk_dw + 576, rawK0, dc, dr0, B2a);  // Khat a
    dw_write<false, true>(qk_dw + 576, rawK1, dc, dr0, B2b);  // Khat b
    __syncthreads();                                    // 5  (Vt/Khat/Qhat ready)
    v8s rawV0[4], rawV1[4];
    dw_read(B0a, dc, dr0, rawV0);                       // Vt a
    dw_read(B0b, dc, dr0, rawV1);                       // Vt b
    v4f S0[4], S1[4];
    mm_lds(B1a, B2a, wv, L, q, S0);                     // S a
    mm_lds(B1b, B2b, wv, L, q, S1);                     // S b
    softmax_to_lds(S0, invt, B1a, rowb, L);             // A a -> B1a (own rows)
    softmax_to_lds(S1, invt, B1b, rowb, L);             // A b -> B1b (own rows)
    __syncthreads();                                    // 6  (B0 reads done)
    dw_write<true, false>(v_dw, rawV0, dc, dr0, B0a);   // V^T a -> B0a
    dw_write<true, false>(v_dw, rawV1, dc, dr0, B0b);   // V^T b -> B0b
    __syncthreads();                                    // 7  (V^T ready)
    v4f O0[4], O1[4];
    mm_lds(B1a, B0a, wv, L, q, O0);                     // O a = A @ V
    mm_lds(B1b, B0b, wv, L, q, O1);                     // O b
#pragma unroll
    for (int nt = 0; nt < 4; ++nt)
#pragma unroll
        for (int r = 0; r < 4; ++r) {
            B2a[(L + 16 * nt) * XS + rowb + r] = f16r(O0[nt][r]);  // O^T a
            B2b[(L + 16 * nt) * XS + rowb + r] = f16r(O1[nt][r]);  // O^T b
        }
    __syncthreads();                                    // 8
    v4f C0[4], C1[4];
    proj_mm(Wp0, B2a, wv, L, q, C0);
    proj_mm(Wp0, B2b, wv, L, q, C1);
#pragma unroll
    for (int nt = 0; nt < 4; ++nt)
#pragma unroll
        for (int r = 0; r < 4; ++r) {
            const int o = rowb + r, p = L + 16 * nt;
            const int yy = ((o >> 5) << 3) + (p >> 3);
            const int xp = ((o & 31) << 3) + (p & 7);
            midb[base0 + yy * 256 + xp] = f16r(C0[nt][r]);
            midb[base1 + yy * 256 + xp] = f16r(C1[nt][r]);
        }
}

// ---------------------------------------------------------------------------
// Branch 2, 2 windows/block. Per-tile schedule = round-7 verified 3-buffer:
// B0: in -> Vt -> V^T ; B1: Qt -> Qhat -> A ; B2: Kt -> Khat -> O^T.
// 7 barriers. Reads mid with roll(-4,-4); writes fp32 out with roll(+4,+4).
// ---------------------------------------------------------------------------
__global__ __launch_bounds__(256, 2) void k2(
    const u16* __restrict__ midb, const float* __restrict__ temp_p,
    const float* __restrict__ qkv_dw,
    const u16* __restrict__ Wqkv, const u16* __restrict__ Wp1,
    float* __restrict__ out)
{
    __shared__ u16 B0a[64 * XS], B1a[64 * XS], B2a[64 * XS];
    __shared__ u16 B0b[64 * XS], B1b[64 * XS], B2b[64 * XS];
    const int t = threadIdx.x;
    const int m0 = blockIdx.x << 1, m1 = m0 + 1;
    const int lane = t & 63, wv = t >> 6, L = lane & 15, q = lane >> 4;
    const int rowb = 16 * wv + 4 * q;
    const int plane0 = m0 >> 4, mh0 = m0 & 15;
    const int plane1 = m1 >> 4, mh1 = m1 & 15;
    const u16* img0 = midb + ((size_t)plane0 << 16);
    const u16* img1 = midb + ((size_t)plane1 << 16);
    const float invt = 1.0f / temp_p[0];
    const int yp = t >> 4, xx0 = (t & 15) << 4;
    const int c2b = (yp >> 3) << 5, ir = (yp & 7) << 3;
    const int dc = t >> 2, dr0 = (t & 3) << 1;

    {   // P1: shifted strips -> B0{a,b} (pure f16 copy)
        const int row0 = (mh0 * 16 + 4 + yp) & 255;
        const int row1 = (mh1 * 16 + 4 + yp) & 255;
#pragma unroll
        for (int k = 0; k < 4; ++k) {
            const int cc = (xx0 + 4 + 4 * k) & 255;
            ushort4 a0 = *(const ushort4*)(img0 + row0 * 256 + cc);
            ushort4 a1 = *(const ushort4*)(img1 + row1 * 256 + cc);
            const int xx = xx0 + 4 * k;
            const int c = c2b + (xx >> 3), pb = ir + (xx & 7);
            B0a[(pb + 0) * XS + c] = a0.x;
            B0a[(pb + 1) * XS + c] = a0.y;
            B0a[(pb + 2) * XS + c] = a0.z;
            B0a[(pb + 3) * XS + c] = a0.w;
            B0b[(pb + 0) * XS + c] = a1.x;
            B0b[(pb + 1) * XS + c] = a1.y;
            B0b[(pb + 2) * XS + c] = a1.z;
            B0b[(pb + 3) * XS + c] = a1.w;
        }
    }
    __syncthreads();                                    // 1
    mm_stage(Wqkv,        B0a, B1a, wv, L, q);          // Qt a
    mm_stage(Wqkv + 4096, B0a, B2a, wv, L, q);          // Kt a
    v4f VF0[4], VF1[4];
    mm_frags(Wqkv + 8192, B0a, wv, L, q, VF0);          // Vt frags a
    mm_stage(Wqkv,        B0b, B1b, wv, L, q);          // Qt b
    mm_stage(Wqkv + 4096, B0b, B2b, wv, L, q);          // Kt b
    mm_frags(Wqkv + 8192, B0b, wv, L, q, VF1);          // Vt frags b
    __syncthreads();                                    // 2  (B0 reads done)
    mm_store(VF0, B0a, wv, L, q);                       // Vt a -> B0a in-place
    mm_store(VF1, B0b, wv, L, q);                       // Vt b -> B0b in-place
    v8s rawQ0[4], rawQ1[4];
    dw_read(B1a, dc, dr0, rawQ0);
    dw_read(B1b, dc, dr0, rawQ1);
    __syncthreads();                                    // 3  (Vt ready; B1 reads done)
    dw_write<false, true>(qkv_dw, rawQ0, dc, dr0, B1a); // Qhat a
    dw_write<false, true>(qkv_dw, rawQ1, dc, dr0, B1b); // Qhat b
    v8s rawK0[4], rawK1[4];
    dw_read(B2a, dc, dr0, rawK0);
    dw_read(B2b, dc, dr0, rawK1);
    v8s rawV0[4], rawV1[4];
    dw_read(B0a, dc, dr0, rawV0);                       // Vt a
    dw_read(B0b, dc, dr0, rawV1);                       // Vt b
    __syncthreads();                                    // 4  (B0/B2 reads done)
    dw_write<false, true>(qkv_dw + 576, rawK0, dc, dr0, B2a);   // Khat a
    dw_write<false, true>(qkv_dw + 576, rawK1, dc, dr0, B2b);   // Khat b
    dw_write<true, false>(qkv_dw + 1152, rawV0, dc, dr0, B0a);  // V^T a
    dw_write<true, false>(qkv_dw + 1152, rawV1, dc, dr0, B0b);  // V^T b
    __syncthreads();                                    // 5  (Qhat/Khat/V^T ready)
    v4f S0[4], S1[4];
    mm_lds(B1a, B2a, wv, L, q, S0);
    mm_lds(B1b, B2b, wv, L, q, S1);
    softmax_to_lds(S0, invt, B1a, rowb, L);             // A a (own rows)
    softmax_to_lds(S1, invt, B1b, rowb, L);             // A b (own rows)
    v4f O0[4], O1[4];
    mm_lds(B1a, B0a, wv, L, q, O0);                     // O a = A @ V
    mm_lds(B1b, B0b, wv, L, q, O1);                     // O b
    __syncthreads();                                    // 6  (B2 S-reads done)
#pragma unroll
    for (int nt = 0; nt < 4; ++nt)
#pragma unroll
        for (int r = 0; r < 4; ++r) {
            B2a[(L + 16 * nt) * XS + rowb + r] = f16r(O0[nt][r]);  // O^T a
            B2b[(L + 16 * nt) * XS + rowb + r] = f16r(O1[nt][r]);  // O^T b
        }
    __syncthreads();                                    // 7
    v4f C0[4], C1[4];
    proj_mm(Wp1, B2a, wv, L, q, C0);
    proj_mm(Wp1, B2b, wv, L, q, C1);
    float* op0 = out + ((size_t)plane0 << 16);
    float* op1 = out + ((size_t)plane1 << 16);
#pragma unroll
    for (int nt = 0; nt < 4; ++nt)
#pragma unroll
        for (int r = 0; r < 4; ++r) {
            const int o = rowb + r, p = L + 16 * nt;
            const int yb = ((o >> 5) << 3) + (p >> 3);
            const int ocol = ((o & 31) * 8 + (p & 7) + 4) & 255;
            const int orow0 = (mh0 * 16 + yb + 4) & 255;
            const int orow1 = (mh1 * 16 + yb + 4) & 255;
            op0[orow0 * 256 + ocol] = C0[nt][r];
            op1[orow1 * 256 + ocol] = C1[nt][r];
        }
}

extern "C" void kernel_launch(void* const* d_in, const int* in_sizes, int n_in,
                              void* d_out, int out_size, void* d_ws, size_t ws_size,
                              hipStream_t stream)
{
    const float* x       = (const float*)d_in[0];
    const float* xf      = (const float*)d_in[1];
    const float* temp    = (const float*)d_in[2];
    const float* qk_w    = (const float*)d_in[3];
    const float* qk_dw   = (const float*)d_in[4];
    const float* v_w     = (const float*)d_in[5];
    const float* v_dw    = (const float*)d_in[6];
    const float* proj_w  = (const float*)d_in[7];
    const float* proj1_w = (const float*)d_in[8];
    const float* qkv1_w  = (const float*)d_in[9];
    const float* qkv1_dw = (const float*)d_in[10];
    float* out = (float*)d_out;

    u16* midb = (u16*)d_ws;                               // 33554432 B
    u16* Wb   = (u16*)((char*)d_ws + 33554432);           // 196608 B

    prep<<<384, 256, 0, stream>>>(qk_w, v_w, qkv1_w, proj_w, proj1_w, Wb);
    k1<<<2048, 256, 0, stream>>>(x, xf, temp, qk_dw, v_dw,
                                 Wb, Wb + 8192, Wb + 24576, midb);
    k2<<<2048, 256, 0, stream>>>(midb, temp, qkv1_dw,
                                 Wb + 12288, Wb + 61440, out);
}